// Round 11
// baseline (417.058 us; speedup 1.0000x reference)
//
#include <hip/hip_runtime.h>
#include <hip/hip_bf16.h>

// Problem constants (fixed by the reference)
#define NN 50000      // nodes
#define EE 800000     // raw edges
#define TE 850000     // edges + self loops
#define NCH 196       // ceil(NN/256) chunks for the scan

typedef __hip_bfloat16 bf16;
typedef __attribute__((ext_vector_type(8))) short short8v;   // 8 bf16 = 4 VGPR
typedef __attribute__((ext_vector_type(4))) float float4v;   // MFMA C/D

__device__ __forceinline__ float b2f(bf16 v) { return __bfloat162float(v); }
__device__ __forceinline__ float bu2f(unsigned short v) {
    return __uint_as_float((unsigned)v << 16);
}
__device__ __forceinline__ unsigned short f2bu(float v) {
    bf16 t = __float2bfloat16(v);
    return *(unsigned short*)&t;
}
__device__ __forceinline__ float lrelu(float e) { return (e > 0.f) ? e : 0.2f * e; }
__device__ __forceinline__ int clampn(int v) {
    return (v < 0) ? 0 : (v >= NN ? NN - 1 : v);
}

// Per-block int64 detection: first 64 odd words of edge_index are all zero iff
// the tensor is int64 (high words of small positives). L1-hot after block 0.
__device__ __forceinline__ int block_isi64(const void* ei) {
    __shared__ int sflag;
    int t = threadIdx.x;
    if (t < 64) {
        unsigned z = (((const unsigned*)ei)[2 * t + 1] == 0u) ? 1u : 0u;
        unsigned long long m = __ballot(z);
        if (t == 0) sflag = (__popcll(m) >= 32) ? 1 : 0;
    }
    __syncthreads();
    return sflag;
}

// ---------------- CSR build (by dst), 2 edges/thread ----------------

__global__ void count_deg_k(const void* __restrict__ ei, int* __restrict__ deg) {
    int isi64 = block_isi64(ei);
    int p = blockIdx.x * 256 + threadIdx.x;      // pair index
    int i0 = p * 2;
    if (i0 >= TE) return;
    int d0, d1 = -1;
    if (i0 + 1 < EE) {
        if (isi64) {
            longlong2 v = ((const longlong2*)ei)[(EE >> 1) + p];
            d0 = clampn((int)v.x); d1 = clampn((int)v.y);
        } else {
            int2 v = ((const int2*)ei)[(EE >> 1) + p];
            d0 = clampn(v.x); d1 = clampn(v.y);
        }
    } else {
        d0 = (i0 < EE) ? clampn(isi64 ? (int)((const long long*)ei)[EE + i0]
                                      : ((const int*)ei)[EE + i0])
                       : (i0 - EE);
        if (i0 + 1 < TE)
            d1 = (i0 + 1 < EE) ? clampn(isi64 ? (int)((const long long*)ei)[EE + i0 + 1]
                                              : ((const int*)ei)[EE + i0 + 1])
                               : (i0 + 1 - EE);
    }
    atomicAdd(&deg[d0], 1);
    if (d1 >= 0) atomicAdd(&deg[d1], 1);
}

__global__ void scan_chunks_k(const int* __restrict__ deg, int* __restrict__ chunkoff) {
    __shared__ int s[256];
    int t = threadIdx.x;
    int sum = 0;
    if (t < NCH) {
        const int4* d4 = (const int4*)(deg + t * 256);
        int lim = (t == NCH - 1) ? (NN - t * 256) : 256;
        int i = 0;
        for (; i + 4 <= lim; i += 4) {
            int4 v = d4[i >> 2];
            sum += v.x + v.y + v.z + v.w;
        }
        for (; i < lim; ++i) sum += deg[t * 256 + i];
    }
    s[t] = sum;
    __syncthreads();
    for (int d = 1; d < 256; d <<= 1) {
        int v = (t >= d) ? s[t - d] : 0;
        __syncthreads();
        s[t] += v;
        __syncthreads();
    }
    if (t < NCH) chunkoff[t] = s[t] - sum;
}

__global__ void scan_within_k(const int* __restrict__ deg, const int* __restrict__ chunkoff,
                              int* __restrict__ offs) {
    __shared__ int s[256];
    int t = threadIdx.x, b = blockIdx.x, i = b * 256 + t;
    int v = (i < NN) ? deg[i] : 0;
    s[t] = v;
    __syncthreads();
    for (int d = 1; d < 256; d <<= 1) {
        int u = (t >= d) ? s[t - d] : 0;
        __syncthreads();
        s[t] += u;
        __syncthreads();
    }
    if (i < NN) offs[i] = chunkoff[b] + s[t] - v;
    if (i == NN - 1) offs[NN] = chunkoff[b] + s[t];
}

// Reverse-fill: slot = offs[d] + (--deg[d]); deg consumed (scans already done).
__global__ void fill_csr_k(const void* __restrict__ ei, const int* __restrict__ offs,
                           int* __restrict__ deg, int* __restrict__ csr_src) {
    int isi64 = block_isi64(ei);
    int p = blockIdx.x * 256 + threadIdx.x;
    int i0 = p * 2;
    if (i0 >= TE) return;
    int s0, d0, s1 = -1, d1 = -1;
    if (i0 + 1 < EE) {
        if (isi64) {
            longlong2 sv = ((const longlong2*)ei)[p];
            longlong2 dv = ((const longlong2*)ei)[(EE >> 1) + p];
            s0 = clampn((int)sv.x); s1 = clampn((int)sv.y);
            d0 = clampn((int)dv.x); d1 = clampn((int)dv.y);
        } else {
            int2 sv = ((const int2*)ei)[p];
            int2 dv = ((const int2*)ei)[(EE >> 1) + p];
            s0 = clampn(sv.x); s1 = clampn(sv.y);
            d0 = clampn(dv.x); d1 = clampn(dv.y);
        }
    } else {
        auto lde = [&](long long idx) {
            return clampn(isi64 ? (int)((const long long*)ei)[idx] : ((const int*)ei)[idx]);
        };
        if (i0 < EE) { s0 = lde(i0); d0 = lde((long long)EE + i0); }
        else         { s0 = i0 - EE; d0 = i0 - EE; }
        if (i0 + 1 < TE) {
            if (i0 + 1 < EE) { s1 = lde(i0 + 1); d1 = lde((long long)EE + i0 + 1); }
            else             { s1 = i0 + 1 - EE; d1 = i0 + 1 - EE; }
        }
    }
    int pos0 = offs[d0] + atomicSub(&deg[d0], 1) - 1;
    csr_src[pos0] = s0;
    if (d1 >= 0) {
        int pos1 = offs[d1] + atomicSub(&deg[d1], 1) - 1;
        csr_src[pos1] = s1;
    }
}

// Canonicalize bucket order: wave per dst, rank-sort -> deterministic content.
__global__ __launch_bounds__(256) void rank_csr_k(const int* __restrict__ offs,
                                                  const int* __restrict__ csr_in,
                                                  int* __restrict__ csr_out) {
    int wv = threadIdx.x >> 6, lane = threadIdx.x & 63;
    int dst = blockIdx.x * 4 + wv;
    if (dst >= NN) return;
    int s = offs[dst], e = offs[dst + 1];
    int d = e - s;
    if (d <= 64) {
        int v = (lane < d) ? csr_in[s + lane] : 0x7fffffff;
        int rank = 0;
        for (int j = 0; j < d; ++j) {
            int vj = __shfl(v, j, 64);
            rank += (vj < v || (vj == v && j < lane)) ? 1 : 0;
        }
        if (lane < d) csr_out[s + rank] = v;
    } else {
        for (int i = lane; i < d; i += 64) {
            int v = csr_in[s + i];
            int rank = 0;
            for (int j = 0; j < d; ++j) {
                int vj = csr_in[s + j];
                rank += (vj < v || (vj == v && j < i)) ? 1 : 0;
            }
            csr_out[s + rank] = v;
        }
    }
}

// ---------------- bf16 pre-convert: xbf = bf16(x); W1T[n][k] = bf16(W1[k][n])
#define XQ (NN * 128 / 4)        // 1.6M float4 groups
__global__ void conv_k(const float* __restrict__ x, const float* __restrict__ W1,
                       unsigned short* __restrict__ xbf, unsigned short* __restrict__ W1T) {
    int i = blockIdx.x * 256 + threadIdx.x;
    if (i < XQ) {
        float4 v = ((const float4*)x)[i];
        ushort4 s;
        s.x = f2bu(v.x); s.y = f2bu(v.y); s.z = f2bu(v.z); s.w = f2bu(v.w);
        ((ushort4*)xbf)[i] = s;
    } else {
        int j = i - XQ;
        if (j < 128 * 256) {
            int n = j >> 7, k = j & 127;
            W1T[j] = f2bu(W1[k * 256 + n]);
        }
    }
}

// ---------------- Layer 1 GEMM on MFMA: h1 = x@W1 (bf16) + alpha partials ---
// Block 256 = 4 waves; wave = 16 rows. 16 col-tiles (= heads) x 4 k-steps of
// mfma_f32_16x16x32_bf16. A[m=lane&15][k=quad*8+j]; B[k=quad*8+j][n=lane&15];
// C col=lane&15, row=quad*4+reg [HW-verified mappings].
__global__ __launch_bounds__(256) void gemm1_k(
    const unsigned short* __restrict__ xbf, const unsigned short* __restrict__ W1T,
    const float* __restrict__ asr, const float* __restrict__ ads,
    bf16* __restrict__ h1, float* __restrict__ a_src, float* __restrict__ a_dst) {
    int wv = threadIdx.x >> 6, lane = threadIdx.x & 63;
    int m = lane & 15, quad = lane >> 4;
    int row0 = blockIdx.x * 64 + wv * 16;
    int arow = row0 + m;
    int arowc = (arow < NN) ? arow : NN - 1;
    short8v a[4];
#pragma unroll
    for (int ks = 0; ks < 4; ++ks)
        a[ks] = *(const short8v*)&xbf[(size_t)arowc * 128 + ks * 32 + quad * 8];
    float4v acc[16];
#pragma unroll
    for (int t = 0; t < 16; ++t) {
        float4v c = {0.f, 0.f, 0.f, 0.f};
        const unsigned short* wb = &W1T[(size_t)(t * 16 + m) * 128 + quad * 8];
#pragma unroll
        for (int ks = 0; ks < 4; ++ks) {
            short8v b = *(const short8v*)&wb[ks * 32];
            c = __builtin_amdgcn_mfma_f32_16x16x32_bf16(a[ks], b, c, 0, 0, 0);
        }
        acc[t] = c;
    }
    // epilogue: rows quad*4+r, col t*16+m
#pragma unroll
    for (int t = 0; t < 16; ++t) {
        float as = asr[t * 16 + m];
        float ad = ads[t * 16 + m];
#pragma unroll
        for (int r = 0; r < 4; ++r) {
            int orow = row0 + quad * 4 + r;
            float v = acc[t][r];
            if (orow < NN) h1[(size_t)orow * 256 + t * 16 + m] = __float2bfloat16(v);
            float ps = v * as, pd = v * ad;
            ps += __shfl_xor(ps, 1, 64); pd += __shfl_xor(pd, 1, 64);
            ps += __shfl_xor(ps, 2, 64); pd += __shfl_xor(pd, 2, 64);
            ps += __shfl_xor(ps, 4, 64); pd += __shfl_xor(pd, 4, 64);
            ps += __shfl_xor(ps, 8, 64); pd += __shfl_xor(pd, 8, 64);
            if (m == 0 && orow < NN) {
                a_src[orow * 16 + t] = ps;
                a_dst[orow * 16 + t] = pd;
            }
        }
    }
}

// ---------------- Layer 1 aggregation: wave-per-dst, 4-edge tiles -----------
__global__ __launch_bounds__(256) void agg1_k(
    const int* __restrict__ offs, const int* __restrict__ csr_src,
    const float* __restrict__ a_src, const float* __restrict__ a_dst,
    const bf16* __restrict__ h1, const float* __restrict__ b1,
    bf16* __restrict__ out1) {
    int wv = threadIdx.x >> 6, lane = threadIdx.x & 63;
    int dst = blockIdx.x * 4 + wv;          // grid = NN/4 exactly
    int start = offs[dst], end = offs[dst + 1];
    int we = lane >> 4, wh = lane & 15;     // weight role
    int hc = lane >> 2;                      // consumer head
    float adst_w = a_dst[dst * 16 + wh];
    float ax = 0.f, ay = 0.f, az = 0.f, aw = 0.f;
    float dsum = 0.f;
    int t0 = start;
    for (; t0 + 4 <= end; t0 += 4) {
        int sr = csr_src[t0 + we];
        float wr = __expf(lrelu(a_src[sr * 16 + wh] + adst_w));
        dsum += wr;
#pragma unroll
        for (int j = 0; j < 4; ++j) {
            int sl = j * 16 + hc;
            float wj = __shfl(wr, sl, 64);
            int sj = __shfl(sr, sl, 64);
            ushort4 hv = *(const ushort4*)&h1[(size_t)sj * 256 + lane * 4];
            ax += wj * bu2f(hv.x);
            ay += wj * bu2f(hv.y);
            az += wj * bu2f(hv.z);
            aw += wj * bu2f(hv.w);
        }
    }
    if (t0 < end) {
        int n = end - t0;
        float wr = 0.f; int sr = 0;
        if (we < n) {
            sr = csr_src[t0 + we];
            wr = __expf(lrelu(a_src[sr * 16 + wh] + adst_w));
        }
        dsum += wr;
        for (int j = 0; j < n; ++j) {
            int sl = j * 16 + hc;
            float wj = __shfl(wr, sl, 64);
            int sj = __shfl(sr, sl, 64);
            ushort4 hv = *(const ushort4*)&h1[(size_t)sj * 256 + lane * 4];
            ax += wj * bu2f(hv.x);
            ay += wj * bu2f(hv.y);
            az += wj * bu2f(hv.z);
            aw += wj * bu2f(hv.w);
        }
    }
    dsum += __shfl_xor(dsum, 16, 64);
    dsum += __shfl_xor(dsum, 32, 64);
    float invd = 1.f / (__shfl(dsum, hc, 64) + 1e-16f);
    float4 bv = *(const float4*)&b1[lane * 4];
    ushort4 st;
    st.x = f2bu(ax * invd + bv.x);
    st.y = f2bu(ay * invd + bv.y);
    st.z = f2bu(az * invd + bv.z);
    st.w = f2bu(aw * invd + bv.w);
    *(ushort4*)&out1[(size_t)dst * 256 + lane * 4] = st;
}

// ---------------- Layer 2 GEMM: h2 = out1@W2 (bf16 out) + alpha2 ------------
__global__ __launch_bounds__(256) void gemm2_k(
    const bf16* __restrict__ out1, const float* __restrict__ W2,
    const float* __restrict__ asr2, const float* __restrict__ ads2,
    bf16* __restrict__ h2, float* __restrict__ a_src2, float* __restrict__ a_dst2) {
    __shared__ bf16 ys[64 * 256];   // 32 KB
    int tid = threadIdx.x;
    int base = blockIdx.x * 64;
    uint4* ys16 = (uint4*)ys;
    const uint4* in16 = (const uint4*)out1;
    for (int i = tid; i < 2048; i += 256) {
        int row = base + (i >> 5);
        uint4 z; z.x = z.y = z.z = z.w = 0u;
        ys16[i] = (row < NN) ? in16[(size_t)base * 32 + i] : z;
    }
    __syncthreads();
    int cg = tid & 31, rg = tid >> 5;
    int c0 = cg * 2;
    float2 acc[8];
#pragma unroll
    for (int r = 0; r < 8; ++r) acc[r] = make_float2(0.f, 0.f);
    for (int kq = 0; kq < 64; ++kq) {
        float2 w0 = *(const float2*)&W2[(kq * 4 + 0) * 64 + c0];
        float2 w1 = *(const float2*)&W2[(kq * 4 + 1) * 64 + c0];
        float2 w2 = *(const float2*)&W2[(kq * 4 + 2) * 64 + c0];
        float2 w3 = *(const float2*)&W2[(kq * 4 + 3) * 64 + c0];
#pragma unroll
        for (int r = 0; r < 8; ++r) {
            const __hip_bfloat162* yp =
                (const __hip_bfloat162*)&ys[(rg * 8 + r) * 256 + kq * 4];
            float2 y01 = __bfloat1622float2(yp[0]);
            float2 y23 = __bfloat1622float2(yp[1]);
            acc[r].x += y01.x * w0.x + y01.y * w1.x + y23.x * w2.x + y23.y * w3.x;
            acc[r].y += y01.x * w0.y + y01.y * w1.y + y23.x * w2.y + y23.y * w3.y;
        }
    }
    float sa0 = asr2[c0], sa1 = asr2[c0 + 1];
    float da0 = ads2[c0], da1 = ads2[c0 + 1];
#pragma unroll
    for (int r = 0; r < 8; ++r) {
        int row = base + rg * 8 + r;
        if (row < NN) {
            __hip_bfloat162 hb;
            hb.x = __float2bfloat16(acc[r].x);
            hb.y = __float2bfloat16(acc[r].y);
            *(__hip_bfloat162*)&h2[(size_t)row * 64 + c0] = hb;
            float ps = acc[r].x * sa0 + acc[r].y * sa1;
            float pd = acc[r].x * da0 + acc[r].y * da1;
#pragma unroll
            for (int o = 1; o <= 16; o <<= 1) {
                ps += __shfl_xor(ps, o, 64);
                pd += __shfl_xor(pd, o, 64);
            }
            if (cg == 0) { a_src2[row] = ps; a_dst2[row] = pd; }
        }
    }
}

// ---------------- Layer 2 aggregation + sigmoid (f32 out) -------------------
__global__ __launch_bounds__(256) void agg2_k(
    const int* __restrict__ offs, const int* __restrict__ csr_src,
    const float* __restrict__ a_src2, const float* __restrict__ a_dst2,
    const bf16* __restrict__ h2, const float* __restrict__ b2,
    float* __restrict__ out) {
    int wv = threadIdx.x >> 6;
    int lane = threadIdx.x & 63;
    int dst = blockIdx.x * 4 + wv;
    if (dst >= NN) return;
    int start = offs[dst], end = offs[dst + 1];
    float adst = a_dst2[dst];
    float acc = 0.f, dsum = 0.f;
    for (int t0 = start; t0 < end; t0 += 64) {
        int n = end - t0; if (n > 64) n = 64;
        float wr = 0.f; int sr = 0;
        if (lane < n) {
            sr = csr_src[t0 + lane];
            wr = __expf(lrelu(a_src2[sr] + adst));
        }
        dsum += wr;
        int j = 0;
        for (; j + 4 <= n; j += 4) {
            float w0 = __shfl(wr, j, 64),     w1 = __shfl(wr, j + 1, 64);
            float w2 = __shfl(wr, j + 2, 64), w3 = __shfl(wr, j + 3, 64);
            int s0 = __shfl(sr, j, 64),       s1 = __shfl(sr, j + 1, 64);
            int s2 = __shfl(sr, j + 2, 64),   s3 = __shfl(sr, j + 3, 64);
            float h0 = b2f(h2[(size_t)s0 * 64 + lane]);
            float h1v = b2f(h2[(size_t)s1 * 64 + lane]);
            float h2v = b2f(h2[(size_t)s2 * 64 + lane]);
            float h3 = b2f(h2[(size_t)s3 * 64 + lane]);
            acc += w0 * h0 + w1 * h1v + w2 * h2v + w3 * h3;
        }
        for (; j < n; ++j) {
            float wj = __shfl(wr, j, 64);
            int sj = __shfl(sr, j, 64);
            acc += wj * b2f(h2[(size_t)sj * 64 + lane]);
        }
    }
#pragma unroll
    for (int o = 32; o >= 1; o >>= 1) dsum += __shfl_xor(dsum, o, 64);
    float o = acc / (dsum + 1e-16f) + b2[lane];
    out[(size_t)dst * 64 + lane] = 1.f / (1.f + __expf(-o));
}

// ---------------- host ------------------------------------------------------

extern "C" void kernel_launch(void* const* d_in, const int* in_sizes, int n_in,
                              void* d_out, int out_size, void* d_ws, size_t ws_size,
                              hipStream_t stream) {
    const float* x    = (const float*)d_in[0];
    const void*  ei   = d_in[1];
    const float* W1   = (const float*)d_in[2];
    const float* asr1 = (const float*)d_in[3];
    const float* ads1 = (const float*)d_in[4];
    const float* b1   = (const float*)d_in[5];
    const float* W2   = (const float*)d_in[6];
    const float* asr2 = (const float*)d_in[7];
    const float* ads2 = (const float*)d_in[8];
    const float* b2   = (const float*)d_in[9];
    float* out = (float*)d_out;

    char* w = (char*)d_ws;
    auto carve = [&](size_t bytes) {
        void* p = (void*)w;
        w += (bytes + 255) & ~(size_t)255;
        return p;
    };
    int*    csr_raw  = (int*)carve((size_t)TE * 4);            // 3.4 MB
    int*    csr_can  = (int*)carve((size_t)TE * 4);            // 3.4 MB (canonical)
    int*    offs     = (int*)carve((size_t)(NN + 1) * 4);
    int*    deg      = (int*)carve((size_t)NN * 4);
    int*    chunkoff = (int*)carve(256 * 4);
    float*  a_src1   = (float*)carve((size_t)NN * 16 * 4);     // 3.2 MB
    float*  a_dst1   = (float*)carve((size_t)NN * 16 * 4);     // 3.2 MB
    unsigned short* xbf = (unsigned short*)carve((size_t)NN * 128 * 2);  // 12.8 MB
    unsigned short* W1T = (unsigned short*)carve(128 * 256 * 2);         // 64 KB
    bf16*   h1       = (bf16*)carve((size_t)NN * 256 * 2);     // 25.6 MB
    bf16*   out1     = (bf16*)carve((size_t)NN * 256 * 2);     // 25.6 MB
    // layer-2 buffers alias h1 (dead after agg1)
    char*   l2base   = (char*)h1;
    bf16*   h2       = (bf16*)l2base;
    float*  a_src2   = (float*)(l2base + (size_t)NN * 64 * 2);
    float*  a_dst2   = a_src2 + NN;

    hipMemsetAsync(deg, 0, (size_t)NN * 4, stream);

    const int pgrid = ((TE + 1) / 2 + 255) / 256;
    count_deg_k<<<pgrid, 256, 0, stream>>>(ei, deg);
    scan_chunks_k<<<1, 256, 0, stream>>>(deg, chunkoff);
    scan_within_k<<<NCH, 256, 0, stream>>>(deg, chunkoff, offs);
    fill_csr_k<<<pgrid, 256, 0, stream>>>(ei, offs, deg, csr_raw);
    rank_csr_k<<<(NN + 3) / 4, 256, 0, stream>>>(offs, csr_raw, csr_can);

    conv_k<<<(XQ + 128 * 256 + 255) / 256, 256, 0, stream>>>(x, W1, xbf, W1T);
    gemm1_k<<<(NN + 63) / 64, 256, 0, stream>>>(xbf, W1T, asr1, ads1, h1, a_src1, a_dst1);
    agg1_k<<<NN / 4, 256, 0, stream>>>(offs, csr_can, a_src1, a_dst1, h1, b1, out1);
    gemm2_k<<<(NN + 63) / 64, 256, 0, stream>>>(out1, W2, asr2, ads2, h2, a_src2, a_dst2);
    agg2_k<<<(NN + 3) / 4, 256, 0, stream>>>(offs, csr_can, a_src2, a_dst2, h2, b2, out);
}

// Round 12
// 365.883 us; speedup vs baseline: 1.1399x; 1.1399x over previous
//
#include <hip/hip_runtime.h>
#include <hip/hip_bf16.h>

// Problem constants (fixed by the reference)
#define NN 50000      // nodes
#define EE 800000     // raw edges
#define TE 850000     // edges + self loops
#define NCH 196       // ceil(NN/256) chunks for the scan

typedef __hip_bfloat16 bf16;
typedef __attribute__((ext_vector_type(8))) short short8v;   // 8 bf16 = 4 VGPR
typedef __attribute__((ext_vector_type(4))) float float4v;   // MFMA C/D

__device__ __forceinline__ float b2f(bf16 v) { return __bfloat162float(v); }
__device__ __forceinline__ float bu2f(unsigned short v) {
    return __uint_as_float((unsigned)v << 16);
}
__device__ __forceinline__ unsigned short f2bu(float v) {
    bf16 t = __float2bfloat16(v);
    return *(unsigned short*)&t;
}
__device__ __forceinline__ float lrelu(float e) { return (e > 0.f) ? e : 0.2f * e; }
__device__ __forceinline__ int clampn(int v) {
    return (v < 0) ? 0 : (v >= NN ? NN - 1 : v);
}

// Per-block int64 detection: first 64 odd words of edge_index all zero iff int64.
__device__ __forceinline__ int block_isi64(const void* ei) {
    __shared__ int sflag;
    int t = threadIdx.x;
    if (t < 64) {
        unsigned z = (((const unsigned*)ei)[2 * t + 1] == 0u) ? 1u : 0u;
        unsigned long long m = __ballot(z);
        if (t == 0) sflag = (__popcll(m) >= 32) ? 1 : 0;
    }
    __syncthreads();
    return sflag;
}

// ---------------- CSR count + fused weight transposes ----------------
// Blocks 0..127 also emit W1T[n][k]=bf16(W1[k][n]); blocks 128..191 emit W2T.
__global__ void count_deg_k(const void* __restrict__ ei, int* __restrict__ deg,
                            const float* __restrict__ W1, const float* __restrict__ W2,
                            unsigned short* __restrict__ W1T,
                            unsigned short* __restrict__ W2T) {
    int isi64 = block_isi64(ei);
    int b = blockIdx.x, t = threadIdx.x;
    if (b < 128) {
        int j = b * 256 + t;                 // j < 32768
        int n = j >> 7, k = j & 127;
        W1T[j] = f2bu(W1[k * 256 + n]);
    } else if (b < 192) {
        int j = (b - 128) * 256 + t;         // j < 16384
        int n = j >> 8, k = j & 255;
        W2T[j] = f2bu(W2[k * 64 + n]);
    }
    int p = b * 256 + t;                     // pair index
    int i0 = p * 2;
    if (i0 >= TE) return;
    int d0, d1 = -1;
    if (i0 + 1 < EE) {
        if (isi64) {
            longlong2 v = ((const longlong2*)ei)[(EE >> 1) + p];
            d0 = clampn((int)v.x); d1 = clampn((int)v.y);
        } else {
            int2 v = ((const int2*)ei)[(EE >> 1) + p];
            d0 = clampn(v.x); d1 = clampn(v.y);
        }
    } else {
        d0 = (i0 < EE) ? clampn(isi64 ? (int)((const long long*)ei)[EE + i0]
                                      : ((const int*)ei)[EE + i0])
                       : (i0 - EE);
        if (i0 + 1 < TE)
            d1 = (i0 + 1 < EE) ? clampn(isi64 ? (int)((const long long*)ei)[EE + i0 + 1]
                                              : ((const int*)ei)[EE + i0 + 1])
                               : (i0 + 1 - EE);
    }
    atomicAdd(&deg[d0], 1);
    if (d1 >= 0) atomicAdd(&deg[d1], 1);
}

__global__ void scan_chunks_k(const int* __restrict__ deg, int* __restrict__ chunkoff) {
    __shared__ int s[256];
    int t = threadIdx.x;
    int sum = 0;
    if (t < NCH) {
        const int4* d4 = (const int4*)(deg + t * 256);
        int lim = (t == NCH - 1) ? (NN - t * 256) : 256;
        int i = 0;
        for (; i + 4 <= lim; i += 4) {
            int4 v = d4[i >> 2];
            sum += v.x + v.y + v.z + v.w;
        }
        for (; i < lim; ++i) sum += deg[t * 256 + i];
    }
    s[t] = sum;
    __syncthreads();
    for (int d = 1; d < 256; d <<= 1) {
        int v = (t >= d) ? s[t - d] : 0;
        __syncthreads();
        s[t] += v;
        __syncthreads();
    }
    if (t < NCH) chunkoff[t] = s[t] - sum;
}

__global__ void scan_within_k(const int* __restrict__ deg, const int* __restrict__ chunkoff,
                              int* __restrict__ offs) {
    __shared__ int s[256];
    int t = threadIdx.x, b = blockIdx.x, i = b * 256 + t;
    int v = (i < NN) ? deg[i] : 0;
    s[t] = v;
    __syncthreads();
    for (int d = 1; d < 256; d <<= 1) {
        int u = (t >= d) ? s[t - d] : 0;
        __syncthreads();
        s[t] += u;
        __syncthreads();
    }
    if (i < NN) offs[i] = chunkoff[b] + s[t] - v;
    if (i == NN - 1) offs[NN] = chunkoff[b] + s[t];
}

// Reverse-fill: slot = offs[d] + (--deg[d]); deg consumed (scans already done).
__global__ void fill_csr_k(const void* __restrict__ ei, const int* __restrict__ offs,
                           int* __restrict__ deg, int* __restrict__ csr_src) {
    int isi64 = block_isi64(ei);
    int p = blockIdx.x * 256 + threadIdx.x;
    int i0 = p * 2;
    if (i0 >= TE) return;
    int s0, d0, s1 = -1, d1 = -1;
    if (i0 + 1 < EE) {
        if (isi64) {
            longlong2 sv = ((const longlong2*)ei)[p];
            longlong2 dv = ((const longlong2*)ei)[(EE >> 1) + p];
            s0 = clampn((int)sv.x); s1 = clampn((int)sv.y);
            d0 = clampn((int)dv.x); d1 = clampn((int)dv.y);
        } else {
            int2 sv = ((const int2*)ei)[p];
            int2 dv = ((const int2*)ei)[(EE >> 1) + p];
            s0 = clampn(sv.x); s1 = clampn(sv.y);
            d0 = clampn(dv.x); d1 = clampn(dv.y);
        }
    } else {
        auto lde = [&](long long idx) {
            return clampn(isi64 ? (int)((const long long*)ei)[idx] : ((const int*)ei)[idx]);
        };
        if (i0 < EE) { s0 = lde(i0); d0 = lde((long long)EE + i0); }
        else         { s0 = i0 - EE; d0 = i0 - EE; }
        if (i0 + 1 < TE) {
            if (i0 + 1 < EE) { s1 = lde(i0 + 1); d1 = lde((long long)EE + i0 + 1); }
            else             { s1 = i0 + 1 - EE; d1 = i0 + 1 - EE; }
        }
    }
    int pos0 = offs[d0] + atomicSub(&deg[d0], 1) - 1;
    csr_src[pos0] = s0;
    if (d1 >= 0) {
        int pos1 = offs[d1] + atomicSub(&deg[d1], 1) - 1;
        csr_src[pos1] = s1;
    }
}

// ---------------- Layer 1 GEMM on MFMA, x converted in-register -------------
// Block 256 = 4 waves; wave = 16 rows; 16 col-tiles x 4 k-steps of 16x16x32.
__global__ __launch_bounds__(256) void gemm1_k(
    const float* __restrict__ x, const unsigned short* __restrict__ W1T,
    const float* __restrict__ asr, const float* __restrict__ ads,
    bf16* __restrict__ h1, float* __restrict__ a_src, float* __restrict__ a_dst) {
    int wv = threadIdx.x >> 6, lane = threadIdx.x & 63;
    int m = lane & 15, quad = lane >> 4;
    int row0 = blockIdx.x * 64 + wv * 16;
    int arow = row0 + m;
    int arowc = (arow < NN) ? arow : NN - 1;
    const float4* x4 = (const float4*)x;
    short8v a[4];
#pragma unroll
    for (int ks = 0; ks < 4; ++ks) {
        float4 f0 = x4[(size_t)arowc * 32 + ks * 8 + quad * 2];
        float4 f1 = x4[(size_t)arowc * 32 + ks * 8 + quad * 2 + 1];
        union { short8v v; unsigned short u[8]; } ua;
        ua.u[0] = f2bu(f0.x); ua.u[1] = f2bu(f0.y);
        ua.u[2] = f2bu(f0.z); ua.u[3] = f2bu(f0.w);
        ua.u[4] = f2bu(f1.x); ua.u[5] = f2bu(f1.y);
        ua.u[6] = f2bu(f1.z); ua.u[7] = f2bu(f1.w);
        a[ks] = ua.v;
    }
    float4v acc[16];
#pragma unroll
    for (int t = 0; t < 16; ++t) {
        float4v c = {0.f, 0.f, 0.f, 0.f};
        const unsigned short* wb = &W1T[(size_t)(t * 16 + m) * 128 + quad * 8];
#pragma unroll
        for (int ks = 0; ks < 4; ++ks) {
            short8v b = *(const short8v*)&wb[ks * 32];
            c = __builtin_amdgcn_mfma_f32_16x16x32_bf16(a[ks], b, c, 0, 0, 0);
        }
        acc[t] = c;
    }
#pragma unroll
    for (int t = 0; t < 16; ++t) {
        float as = asr[t * 16 + m];
        float ad = ads[t * 16 + m];
#pragma unroll
        for (int r = 0; r < 4; ++r) {
            int orow = row0 + quad * 4 + r;
            float v = acc[t][r];
            if (orow < NN) h1[(size_t)orow * 256 + t * 16 + m] = __float2bfloat16(v);
            float ps = v * as, pd = v * ad;
            ps += __shfl_xor(ps, 1, 64); pd += __shfl_xor(pd, 1, 64);
            ps += __shfl_xor(ps, 2, 64); pd += __shfl_xor(pd, 2, 64);
            ps += __shfl_xor(ps, 4, 64); pd += __shfl_xor(pd, 4, 64);
            ps += __shfl_xor(ps, 8, 64); pd += __shfl_xor(pd, 8, 64);
            if (m == 0 && orow < NN) {
                a_src[orow * 16 + t] = ps;
                a_dst[orow * 16 + t] = pd;
            }
        }
    }
}

// ---------------- Layer 1 aggregation: wave-per-dst, on-the-fly sort --------
// Sorts its bucket (rank-sort d<=64, serial-LDS d<=256), streams from sorted
// LDS, and writes canonical bucket to csr_can for agg2. Deterministic.
__global__ __launch_bounds__(256) void agg1_k(
    const int* __restrict__ offs, const int* __restrict__ csr_raw,
    int* __restrict__ csr_can,
    const float* __restrict__ a_src, const float* __restrict__ a_dst,
    const bf16* __restrict__ h1, const float* __restrict__ b1,
    bf16* __restrict__ out1) {
    __shared__ int sbuf[4][256];
    int wv = threadIdx.x >> 6, lane = threadIdx.x & 63;
    int dst = blockIdx.x * 4 + wv;          // grid = NN/4 exactly
    int start = offs[dst], end = offs[dst + 1];
    int d = end - start;
    // --- canonicalize bucket into sbuf[wv][0..d) ---
    if (d <= 64) {
        int v = (lane < d) ? csr_raw[start + lane] : 0x7fffffff;
        int rank = 0;
        for (int j = 0; j < d; ++j) {
            int vj = __shfl(v, j, 64);
            rank += (vj < v || (vj == v && j < lane)) ? 1 : 0;
        }
        if (lane < d) sbuf[wv][rank] = v;
    } else if (d <= 256) {
        if (lane == 0) {
            for (int i = 0; i < d; ++i) {
                int v = csr_raw[start + i];
                int j = i - 1;
                while (j >= 0 && sbuf[wv][j] > v) { sbuf[wv][j + 1] = sbuf[wv][j]; --j; }
                sbuf[wv][j + 1] = v;
            }
        }
    } else {                                 // physically impossible; raw copy
        for (int i = lane; i < d && i < 256; i += 64) sbuf[wv][i] = csr_raw[start + i];
        if (d > 256) d = 256;
    }
    for (int i = lane; i < d; i += 64) csr_can[start + i] = sbuf[wv][i];
    // --- weighted gather-sum (raw-exp softmax) ---
    int we = lane >> 4, wh = lane & 15;     // weight role
    int hc = lane >> 2;                      // consumer head
    float adst_w = a_dst[dst * 16 + wh];
    float ax = 0.f, ay = 0.f, az = 0.f, aw = 0.f;
    float dsum = 0.f;
    int t0 = 0;
    for (; t0 + 4 <= d; t0 += 4) {
        int sr = sbuf[wv][t0 + we];
        float wr = __expf(lrelu(a_src[sr * 16 + wh] + adst_w));
        dsum += wr;
#pragma unroll
        for (int j = 0; j < 4; ++j) {
            float wj = __shfl(wr, j * 16 + hc, 64);
            int sj = sbuf[wv][t0 + j];
            ushort4 hv = *(const ushort4*)&h1[(size_t)sj * 256 + lane * 4];
            ax += wj * bu2f(hv.x);
            ay += wj * bu2f(hv.y);
            az += wj * bu2f(hv.z);
            aw += wj * bu2f(hv.w);
        }
    }
    if (t0 < d) {
        int n = d - t0;
        float wr = 0.f;
        if (we < n) {
            int sr = sbuf[wv][t0 + we];
            wr = __expf(lrelu(a_src[sr * 16 + wh] + adst_w));
        }
        dsum += wr;
        for (int j = 0; j < n; ++j) {
            float wj = __shfl(wr, j * 16 + hc, 64);
            int sj = sbuf[wv][t0 + j];
            ushort4 hv = *(const ushort4*)&h1[(size_t)sj * 256 + lane * 4];
            ax += wj * bu2f(hv.x);
            ay += wj * bu2f(hv.y);
            az += wj * bu2f(hv.z);
            aw += wj * bu2f(hv.w);
        }
    }
    dsum += __shfl_xor(dsum, 16, 64);
    dsum += __shfl_xor(dsum, 32, 64);
    float invd = 1.f / (__shfl(dsum, hc, 64) + 1e-16f);
    float4 bv = *(const float4*)&b1[lane * 4];
    ushort4 st;
    st.x = f2bu(ax * invd + bv.x);
    st.y = f2bu(ay * invd + bv.y);
    st.z = f2bu(az * invd + bv.z);
    st.w = f2bu(aw * invd + bv.w);
    *(ushort4*)&out1[(size_t)dst * 256 + lane * 4] = st;
}

// ---------------- Layer 2 GEMM on MFMA: h2 = out1@W2 + alpha2 ---------------
// Wave = 16 rows; 4 col-tiles x 8 k-steps (K=256) of 16x16x32 bf16.
__global__ __launch_bounds__(256) void gemm2_k(
    const bf16* __restrict__ out1, const unsigned short* __restrict__ W2T,
    const float* __restrict__ asr2, const float* __restrict__ ads2,
    bf16* __restrict__ h2, float* __restrict__ a_src2, float* __restrict__ a_dst2) {
    int wv = threadIdx.x >> 6, lane = threadIdx.x & 63;
    int m = lane & 15, quad = lane >> 4;
    int row0 = blockIdx.x * 64 + wv * 16;
    int arow = row0 + m;
    int arowc = (arow < NN) ? arow : NN - 1;
    const unsigned short* ab = (const unsigned short*)out1;
    short8v a[8];
#pragma unroll
    for (int ks = 0; ks < 8; ++ks)
        a[ks] = *(const short8v*)&ab[(size_t)arowc * 256 + ks * 32 + quad * 8];
    float4v acc[4];
#pragma unroll
    for (int t = 0; t < 4; ++t) {
        float4v c = {0.f, 0.f, 0.f, 0.f};
        const unsigned short* wb = &W2T[(size_t)(t * 16 + m) * 256 + quad * 8];
#pragma unroll
        for (int ks = 0; ks < 8; ++ks) {
            short8v b = *(const short8v*)&wb[ks * 32];
            c = __builtin_amdgcn_mfma_f32_16x16x32_bf16(a[ks], b, c, 0, 0, 0);
        }
        acc[t] = c;
    }
    float rs[4] = {0.f, 0.f, 0.f, 0.f}, rd[4] = {0.f, 0.f, 0.f, 0.f};
#pragma unroll
    for (int t = 0; t < 4; ++t) {
        float as = asr2[t * 16 + m];
        float ad = ads2[t * 16 + m];
#pragma unroll
        for (int r = 0; r < 4; ++r) {
            int orow = row0 + quad * 4 + r;
            float v = acc[t][r];
            if (orow < NN) h2[(size_t)orow * 64 + t * 16 + m] = __float2bfloat16(v);
            float ps = v * as, pd = v * ad;
            ps += __shfl_xor(ps, 1, 64); pd += __shfl_xor(pd, 1, 64);
            ps += __shfl_xor(ps, 2, 64); pd += __shfl_xor(pd, 2, 64);
            ps += __shfl_xor(ps, 4, 64); pd += __shfl_xor(pd, 4, 64);
            ps += __shfl_xor(ps, 8, 64); pd += __shfl_xor(pd, 8, 64);
            rs[r] += ps; rd[r] += pd;
        }
    }
#pragma unroll
    for (int r = 0; r < 4; ++r) {
        int orow = row0 + quad * 4 + r;
        if (m == 0 && orow < NN) {
            a_src2[orow] = rs[r];
            a_dst2[orow] = rd[r];
        }
    }
}

// ---------------- Layer 2 aggregation + sigmoid (f32 out) -------------------
__global__ __launch_bounds__(256) void agg2_k(
    const int* __restrict__ offs, const int* __restrict__ csr_src,
    const float* __restrict__ a_src2, const float* __restrict__ a_dst2,
    const bf16* __restrict__ h2, const float* __restrict__ b2,
    float* __restrict__ out) {
    int wv = threadIdx.x >> 6;
    int lane = threadIdx.x & 63;
    int dst = blockIdx.x * 4 + wv;
    if (dst >= NN) return;
    int start = offs[dst], end = offs[dst + 1];
    float adst = a_dst2[dst];
    float acc = 0.f, dsum = 0.f;
    for (int t0 = start; t0 < end; t0 += 64) {
        int n = end - t0; if (n > 64) n = 64;
        float wr = 0.f; int sr = 0;
        if (lane < n) {
            sr = csr_src[t0 + lane];
            wr = __expf(lrelu(a_src2[sr] + adst));
        }
        dsum += wr;
        int j = 0;
        for (; j + 4 <= n; j += 4) {
            float w0 = __shfl(wr, j, 64),     w1 = __shfl(wr, j + 1, 64);
            float w2 = __shfl(wr, j + 2, 64), w3 = __shfl(wr, j + 3, 64);
            int s0 = __shfl(sr, j, 64),       s1 = __shfl(sr, j + 1, 64);
            int s2 = __shfl(sr, j + 2, 64),   s3 = __shfl(sr, j + 3, 64);
            float h0 = b2f(h2[(size_t)s0 * 64 + lane]);
            float h1v = b2f(h2[(size_t)s1 * 64 + lane]);
            float h2v = b2f(h2[(size_t)s2 * 64 + lane]);
            float h3 = b2f(h2[(size_t)s3 * 64 + lane]);
            acc += w0 * h0 + w1 * h1v + w2 * h2v + w3 * h3;
        }
        for (; j < n; ++j) {
            float wj = __shfl(wr, j, 64);
            int sj = __shfl(sr, j, 64);
            acc += wj * b2f(h2[(size_t)sj * 64 + lane]);
        }
    }
#pragma unroll
    for (int o = 32; o >= 1; o >>= 1) dsum += __shfl_xor(dsum, o, 64);
    float o = acc / (dsum + 1e-16f) + b2[lane];
    out[(size_t)dst * 64 + lane] = 1.f / (1.f + __expf(-o));
}

// ---------------- host ------------------------------------------------------

extern "C" void kernel_launch(void* const* d_in, const int* in_sizes, int n_in,
                              void* d_out, int out_size, void* d_ws, size_t ws_size,
                              hipStream_t stream) {
    const float* x    = (const float*)d_in[0];
    const void*  ei   = d_in[1];
    const float* W1   = (const float*)d_in[2];
    const float* asr1 = (const float*)d_in[3];
    const float* ads1 = (const float*)d_in[4];
    const float* b1   = (const float*)d_in[5];
    const float* W2   = (const float*)d_in[6];
    const float* asr2 = (const float*)d_in[7];
    const float* ads2 = (const float*)d_in[8];
    const float* b2   = (const float*)d_in[9];
    float* out = (float*)d_out;

    char* w = (char*)d_ws;
    auto carve = [&](size_t bytes) {
        void* p = (void*)w;
        w += (bytes + 255) & ~(size_t)255;
        return p;
    };
    int*    csr_raw  = (int*)carve((size_t)TE * 4);            // 3.4 MB
    int*    csr_can  = (int*)carve((size_t)TE * 4);            // 3.4 MB
    int*    offs     = (int*)carve((size_t)(NN + 1) * 4);
    int*    deg      = (int*)carve((size_t)NN * 4);
    int*    chunkoff = (int*)carve(256 * 4);
    float*  a_src1   = (float*)carve((size_t)NN * 16 * 4);     // 3.2 MB
    float*  a_dst1   = (float*)carve((size_t)NN * 16 * 4);     // 3.2 MB
    unsigned short* W1T = (unsigned short*)carve(128 * 256 * 2);   // 64 KB
    unsigned short* W2T = (unsigned short*)carve(256 * 64 * 2);    // 32 KB
    bf16*   h1       = (bf16*)carve((size_t)NN * 256 * 2);     // 25.6 MB
    bf16*   out1     = (bf16*)carve((size_t)NN * 256 * 2);     // 25.6 MB
    // layer-2 buffers alias h1 (dead after agg1)
    char*   l2base   = (char*)h1;
    bf16*   h2       = (bf16*)l2base;
    float*  a_src2   = (float*)(l2base + (size_t)NN * 64 * 2);
    float*  a_dst2   = a_src2 + NN;

    hipMemsetAsync(deg, 0, (size_t)NN * 4, stream);

    const int pgrid = ((TE + 1) / 2 + 255) / 256;
    count_deg_k<<<pgrid, 256, 0, stream>>>(ei, deg, W1, W2, W1T, W2T);
    scan_chunks_k<<<1, 256, 0, stream>>>(deg, chunkoff);
    scan_within_k<<<NCH, 256, 0, stream>>>(deg, chunkoff, offs);
    fill_csr_k<<<pgrid, 256, 0, stream>>>(ei, offs, deg, csr_raw);

    gemm1_k<<<(NN + 63) / 64, 256, 0, stream>>>(x, W1T, asr1, ads1, h1, a_src1, a_dst1);
    agg1_k<<<NN / 4, 256, 0, stream>>>(offs, csr_raw, csr_can, a_src1, a_dst1, h1, b1, out1);
    gemm2_k<<<(NN + 63) / 64, 256, 0, stream>>>(out1, W2T, asr2, ads2, h2, a_src2, a_dst2);
    agg2_k<<<(NN + 3) / 4, 256, 0, stream>>>(offs, csr_can, a_src2, a_dst2, h2, b2, out);
}

// Round 13
// 353.779 us; speedup vs baseline: 1.1789x; 1.0342x over previous
//
#include <hip/hip_runtime.h>
#include <hip/hip_bf16.h>

// Problem constants (fixed by the reference)
#define NN 50000      // nodes
#define EE 800000     // raw edges
#define TE 850000     // edges + self loops
#define NCH 196       // ceil(NN/256) chunks for the scan

typedef __hip_bfloat16 bf16;
typedef __attribute__((ext_vector_type(8))) short short8v;   // 8 bf16 = 4 VGPR
typedef __attribute__((ext_vector_type(4))) float float4v;   // MFMA C/D

__device__ __forceinline__ float b2f(bf16 v) { return __bfloat162float(v); }
__device__ __forceinline__ float bu2f(unsigned short v) {
    return __uint_as_float((unsigned)v << 16);
}
__device__ __forceinline__ unsigned short f2bu(float v) {
    bf16 t = __float2bfloat16(v);
    return *(unsigned short*)&t;
}
__device__ __forceinline__ float lrelu(float e) { return (e > 0.f) ? e : 0.2f * e; }
__device__ __forceinline__ int clampn(int v) {
    return (v < 0) ? 0 : (v >= NN ? NN - 1 : v);
}

// Per-block int64 detection: first 64 odd words of edge_index all zero iff int64.
__device__ __forceinline__ int block_isi64(const void* ei) {
    __shared__ int sflag;
    int t = threadIdx.x;
    if (t < 64) {
        unsigned z = (((const unsigned*)ei)[2 * t + 1] == 0u) ? 1u : 0u;
        unsigned long long m = __ballot(z);
        if (t == 0) sflag = (__popcll(m) >= 32) ? 1 : 0;
    }
    __syncthreads();
    return sflag;
}

// ---------------- CSR count + fused weight transposes + alpha projections ---
// blocks 0..127: W1T[n][k]. 128..191: W2T[n][k]. 192: P1sT/P1dT[h][k] (128x16
// alpha projections folded through asr1/ads1). 193: P2T (2x256 packed + zeros).
__global__ void count_deg_k(const void* __restrict__ ei, int* __restrict__ deg,
                            const float* __restrict__ W1, const float* __restrict__ W2,
                            const float* __restrict__ asr1, const float* __restrict__ ads1,
                            const float* __restrict__ asr2, const float* __restrict__ ads2,
                            unsigned short* __restrict__ W1T,
                            unsigned short* __restrict__ W2T,
                            unsigned short* __restrict__ P1sT,
                            unsigned short* __restrict__ P1dT,
                            unsigned short* __restrict__ P2T) {
    int isi64 = block_isi64(ei);
    int b = blockIdx.x, t = threadIdx.x;
    if (b < 128) {
        int j = b * 256 + t;                 // j < 32768
        int n = j >> 7, k = j & 127;
        W1T[j] = f2bu(W1[k * 256 + n]);
    } else if (b < 192) {
        int j = (b - 128) * 256 + t;         // j < 16384
        int n = j >> 8, k = j & 255;
        W2T[j] = f2bu(W2[k * 64 + n]);
    } else if (b == 192) {
        for (int j = t; j < 2048; j += 256) {   // P1[h][k], h=j>>7, k=j&127
            int h = j >> 7, k = j & 127;
            float s = 0.f, d = 0.f;
            for (int c = 0; c < 16; ++c) {
                float wv = W1[k * 256 + h * 16 + c];
                s += wv * asr1[h * 16 + c];
                d += wv * ads1[h * 16 + c];
            }
            P1sT[j] = f2bu(s);
            P1dT[j] = f2bu(d);
        }
    } else if (b == 193) {
        // P2T[0][k]=proj_src, P2T[1][k]=proj_dst, rows 2..15 zero (16x256)
        int k = t;
        float s = 0.f, d = 0.f;
        for (int c = 0; c < 64; ++c) {
            float wv = W2[k * 64 + c];
            s += wv * asr2[c];
            d += wv * ads2[c];
        }
        P2T[k] = f2bu(s);
        P2T[256 + k] = f2bu(d);
        for (int j = 512 + t; j < 4096; j += 256) P2T[j] = 0;
    }
    int p = b * 256 + t;                     // pair index
    int i0 = p * 2;
    if (i0 >= TE) return;
    int d0, d1 = -1;
    if (i0 + 1 < EE) {
        if (isi64) {
            longlong2 v = ((const longlong2*)ei)[(EE >> 1) + p];
            d0 = clampn((int)v.x); d1 = clampn((int)v.y);
        } else {
            int2 v = ((const int2*)ei)[(EE >> 1) + p];
            d0 = clampn(v.x); d1 = clampn(v.y);
        }
    } else {
        d0 = (i0 < EE) ? clampn(isi64 ? (int)((const long long*)ei)[EE + i0]
                                      : ((const int*)ei)[EE + i0])
                       : (i0 - EE);
        if (i0 + 1 < TE)
            d1 = (i0 + 1 < EE) ? clampn(isi64 ? (int)((const long long*)ei)[EE + i0 + 1]
                                              : ((const int*)ei)[EE + i0 + 1])
                               : (i0 + 1 - EE);
    }
    atomicAdd(&deg[d0], 1);
    if (d1 >= 0) atomicAdd(&deg[d1], 1);
}

__global__ void scan_chunks_k(const int* __restrict__ deg, int* __restrict__ chunkoff) {
    __shared__ int s[256];
    int t = threadIdx.x;
    int sum = 0;
    if (t < NCH) {
        const int4* d4 = (const int4*)(deg + t * 256);
        int lim = (t == NCH - 1) ? (NN - t * 256) : 256;
        int i = 0;
        for (; i + 4 <= lim; i += 4) {
            int4 v = d4[i >> 2];
            sum += v.x + v.y + v.z + v.w;
        }
        for (; i < lim; ++i) sum += deg[t * 256 + i];
    }
    s[t] = sum;
    __syncthreads();
    for (int d = 1; d < 256; d <<= 1) {
        int v = (t >= d) ? s[t - d] : 0;
        __syncthreads();
        s[t] += v;
        __syncthreads();
    }
    if (t < NCH) chunkoff[t] = s[t] - sum;
}

__global__ void scan_within_k(const int* __restrict__ deg, const int* __restrict__ chunkoff,
                              int* __restrict__ offs) {
    __shared__ int s[256];
    int t = threadIdx.x, b = blockIdx.x, i = b * 256 + t;
    int v = (i < NN) ? deg[i] : 0;
    s[t] = v;
    __syncthreads();
    for (int d = 1; d < 256; d <<= 1) {
        int u = (t >= d) ? s[t - d] : 0;
        __syncthreads();
        s[t] += u;
        __syncthreads();
    }
    if (i < NN) offs[i] = chunkoff[b] + s[t] - v;
    if (i == NN - 1) offs[NN] = chunkoff[b] + s[t];
}

// Reverse-fill: slot = offs[d] + (--deg[d]); deg consumed (scans already done).
__global__ void fill_csr_k(const void* __restrict__ ei, const int* __restrict__ offs,
                           int* __restrict__ deg, int* __restrict__ csr_src) {
    int isi64 = block_isi64(ei);
    int p = blockIdx.x * 256 + threadIdx.x;
    int i0 = p * 2;
    if (i0 >= TE) return;
    int s0, d0, s1 = -1, d1 = -1;
    if (i0 + 1 < EE) {
        if (isi64) {
            longlong2 sv = ((const longlong2*)ei)[p];
            longlong2 dv = ((const longlong2*)ei)[(EE >> 1) + p];
            s0 = clampn((int)sv.x); s1 = clampn((int)sv.y);
            d0 = clampn((int)dv.x); d1 = clampn((int)dv.y);
        } else {
            int2 sv = ((const int2*)ei)[p];
            int2 dv = ((const int2*)ei)[(EE >> 1) + p];
            s0 = clampn(sv.x); s1 = clampn(sv.y);
            d0 = clampn(dv.x); d1 = clampn(dv.y);
        }
    } else {
        auto lde = [&](long long idx) {
            return clampn(isi64 ? (int)((const long long*)ei)[idx] : ((const int*)ei)[idx]);
        };
        if (i0 < EE) { s0 = lde(i0); d0 = lde((long long)EE + i0); }
        else         { s0 = i0 - EE; d0 = i0 - EE; }
        if (i0 + 1 < TE) {
            if (i0 + 1 < EE) { s1 = lde(i0 + 1); d1 = lde((long long)EE + i0 + 1); }
            else             { s1 = i0 + 1 - EE; d1 = i0 + 1 - EE; }
        }
    }
    int pos0 = offs[d0] + atomicSub(&deg[d0], 1) - 1;
    csr_src[pos0] = s0;
    if (d1 >= 0) {
        int pos1 = offs[d1] + atomicSub(&deg[d1], 1) - 1;
        csr_src[pos1] = s1;
    }
}

// ---------------- Layer 1 GEMM on MFMA; alphas via projection MFMAs ---------
// Wave = 16 rows; 16 col-tiles x 4 k-steps + 2x4 alpha-projection MFMAs.
// No epilogue shuffles: alpha C-layout col == head, stores are contiguous.
__global__ __launch_bounds__(256) void gemm1_k(
    const float* __restrict__ x, const unsigned short* __restrict__ W1T,
    const unsigned short* __restrict__ P1sT, const unsigned short* __restrict__ P1dT,
    bf16* __restrict__ h1, float* __restrict__ a_src, float* __restrict__ a_dst) {
    int wv = threadIdx.x >> 6, lane = threadIdx.x & 63;
    int m = lane & 15, quad = lane >> 4;
    int row0 = blockIdx.x * 64 + wv * 16;
    int arow = row0 + m;
    int arowc = (arow < NN) ? arow : NN - 1;
    const float4* x4 = (const float4*)x;
    short8v a[4];
#pragma unroll
    for (int ks = 0; ks < 4; ++ks) {
        float4 f0 = x4[(size_t)arowc * 32 + ks * 8 + quad * 2];
        float4 f1 = x4[(size_t)arowc * 32 + ks * 8 + quad * 2 + 1];
        union { short8v v; unsigned short u[8]; } ua;
        ua.u[0] = f2bu(f0.x); ua.u[1] = f2bu(f0.y);
        ua.u[2] = f2bu(f0.z); ua.u[3] = f2bu(f0.w);
        ua.u[4] = f2bu(f1.x); ua.u[5] = f2bu(f1.y);
        ua.u[6] = f2bu(f1.z); ua.u[7] = f2bu(f1.w);
        a[ks] = ua.v;
    }
    float4v accs = {0.f, 0.f, 0.f, 0.f}, accd = {0.f, 0.f, 0.f, 0.f};
#pragma unroll
    for (int ks = 0; ks < 4; ++ks) {
        short8v bs = *(const short8v*)&P1sT[(size_t)m * 128 + quad * 8 + ks * 32];
        short8v bd = *(const short8v*)&P1dT[(size_t)m * 128 + quad * 8 + ks * 32];
        accs = __builtin_amdgcn_mfma_f32_16x16x32_bf16(a[ks], bs, accs, 0, 0, 0);
        accd = __builtin_amdgcn_mfma_f32_16x16x32_bf16(a[ks], bd, accd, 0, 0, 0);
    }
    float4v acc[16];
#pragma unroll
    for (int t = 0; t < 16; ++t) {
        float4v c = {0.f, 0.f, 0.f, 0.f};
        const unsigned short* wb = &W1T[(size_t)(t * 16 + m) * 128 + quad * 8];
#pragma unroll
        for (int ks = 0; ks < 4; ++ks) {
            short8v b = *(const short8v*)&wb[ks * 32];
            c = __builtin_amdgcn_mfma_f32_16x16x32_bf16(a[ks], b, c, 0, 0, 0);
        }
        acc[t] = c;
    }
#pragma unroll
    for (int t = 0; t < 16; ++t) {
#pragma unroll
        for (int r = 0; r < 4; ++r) {
            int orow = row0 + quad * 4 + r;
            if (orow < NN)
                h1[(size_t)orow * 256 + t * 16 + m] = __float2bfloat16(acc[t][r]);
        }
    }
#pragma unroll
    for (int r = 0; r < 4; ++r) {
        int orow = row0 + quad * 4 + r;
        if (orow < NN) {
            a_src[orow * 16 + m] = accs[r];   // C col == head == m
            a_dst[orow * 16 + m] = accd[r];
        }
    }
}

// ---------------- Layer 1 aggregation: wave-per-dst, on-the-fly sort --------
__global__ __launch_bounds__(256) void agg1_k(
    const int* __restrict__ offs, const int* __restrict__ csr_raw,
    int* __restrict__ csr_can,
    const float* __restrict__ a_src, const float* __restrict__ a_dst,
    const bf16* __restrict__ h1, const float* __restrict__ b1,
    bf16* __restrict__ out1) {
    __shared__ int sbuf[4][256];
    int wv = threadIdx.x >> 6, lane = threadIdx.x & 63;
    int dst = blockIdx.x * 4 + wv;          // grid = NN/4 exactly
    int start = offs[dst], end = offs[dst + 1];
    int d = end - start;
    if (d <= 64) {
        int v = (lane < d) ? csr_raw[start + lane] : 0x7fffffff;
        int rank = 0;
        for (int j = 0; j < d; ++j) {
            int vj = __shfl(v, j, 64);
            rank += (vj < v || (vj == v && j < lane)) ? 1 : 0;
        }
        if (lane < d) sbuf[wv][rank] = v;
    } else if (d <= 256) {
        if (lane == 0) {
            for (int i = 0; i < d; ++i) {
                int v = csr_raw[start + i];
                int j = i - 1;
                while (j >= 0 && sbuf[wv][j] > v) { sbuf[wv][j + 1] = sbuf[wv][j]; --j; }
                sbuf[wv][j + 1] = v;
            }
        }
    } else {
        for (int i = lane; i < d && i < 256; i += 64) sbuf[wv][i] = csr_raw[start + i];
        if (d > 256) d = 256;
    }
    for (int i = lane; i < d; i += 64) csr_can[start + i] = sbuf[wv][i];
    int we = lane >> 4, wh = lane & 15;
    int hc = lane >> 2;
    float adst_w = a_dst[dst * 16 + wh];
    float ax = 0.f, ay = 0.f, az = 0.f, aw = 0.f;
    float dsum = 0.f;
    int t0 = 0;
    for (; t0 + 4 <= d; t0 += 4) {
        int sr = sbuf[wv][t0 + we];
        float wr = __expf(lrelu(a_src[sr * 16 + wh] + adst_w));
        dsum += wr;
#pragma unroll
        for (int j = 0; j < 4; ++j) {
            float wj = __shfl(wr, j * 16 + hc, 64);
            int sj = sbuf[wv][t0 + j];
            ushort4 hv = *(const ushort4*)&h1[(size_t)sj * 256 + lane * 4];
            ax += wj * bu2f(hv.x);
            ay += wj * bu2f(hv.y);
            az += wj * bu2f(hv.z);
            aw += wj * bu2f(hv.w);
        }
    }
    if (t0 < d) {
        int n = d - t0;
        float wr = 0.f;
        if (we < n) {
            int sr = sbuf[wv][t0 + we];
            wr = __expf(lrelu(a_src[sr * 16 + wh] + adst_w));
        }
        dsum += wr;
        for (int j = 0; j < n; ++j) {
            float wj = __shfl(wr, j * 16 + hc, 64);
            int sj = sbuf[wv][t0 + j];
            ushort4 hv = *(const ushort4*)&h1[(size_t)sj * 256 + lane * 4];
            ax += wj * bu2f(hv.x);
            ay += wj * bu2f(hv.y);
            az += wj * bu2f(hv.z);
            aw += wj * bu2f(hv.w);
        }
    }
    dsum += __shfl_xor(dsum, 16, 64);
    dsum += __shfl_xor(dsum, 32, 64);
    float invd = 1.f / (__shfl(dsum, hc, 64) + 1e-16f);
    float4 bv = *(const float4*)&b1[lane * 4];
    ushort4 st;
    st.x = f2bu(ax * invd + bv.x);
    st.y = f2bu(ay * invd + bv.y);
    st.z = f2bu(az * invd + bv.z);
    st.w = f2bu(aw * invd + bv.w);
    *(ushort4*)&out1[(size_t)dst * 256 + lane * 4] = st;
}

// ---------------- Layer 2 GEMM on MFMA; alphas via packed projection --------
__global__ __launch_bounds__(256) void gemm2_k(
    const bf16* __restrict__ out1, const unsigned short* __restrict__ W2T,
    const unsigned short* __restrict__ P2T,
    bf16* __restrict__ h2, float* __restrict__ a_src2, float* __restrict__ a_dst2) {
    int wv = threadIdx.x >> 6, lane = threadIdx.x & 63;
    int m = lane & 15, quad = lane >> 4;
    int row0 = blockIdx.x * 64 + wv * 16;
    int arow = row0 + m;
    int arowc = (arow < NN) ? arow : NN - 1;
    const unsigned short* ab = (const unsigned short*)out1;
    short8v a[8];
#pragma unroll
    for (int ks = 0; ks < 8; ++ks)
        a[ks] = *(const short8v*)&ab[(size_t)arowc * 256 + ks * 32 + quad * 8];
    float4v acca = {0.f, 0.f, 0.f, 0.f};
#pragma unroll
    for (int ks = 0; ks < 8; ++ks) {
        short8v b = *(const short8v*)&P2T[(size_t)m * 256 + quad * 8 + ks * 32];
        acca = __builtin_amdgcn_mfma_f32_16x16x32_bf16(a[ks], b, acca, 0, 0, 0);
    }
    float4v acc[4];
#pragma unroll
    for (int t = 0; t < 4; ++t) {
        float4v c = {0.f, 0.f, 0.f, 0.f};
        const unsigned short* wb = &W2T[(size_t)(t * 16 + m) * 256 + quad * 8];
#pragma unroll
        for (int ks = 0; ks < 8; ++ks) {
            short8v b = *(const short8v*)&wb[ks * 32];
            c = __builtin_amdgcn_mfma_f32_16x16x32_bf16(a[ks], b, c, 0, 0, 0);
        }
        acc[t] = c;
    }
#pragma unroll
    for (int t = 0; t < 4; ++t) {
#pragma unroll
        for (int r = 0; r < 4; ++r) {
            int orow = row0 + quad * 4 + r;
            if (orow < NN)
                h2[(size_t)orow * 64 + t * 16 + m] = __float2bfloat16(acc[t][r]);
        }
    }
#pragma unroll
    for (int r = 0; r < 4; ++r) {
        int orow = row0 + quad * 4 + r;
        if (orow < NN) {
            if (m == 0) a_src2[orow] = acca[r];   // col 0 = src projection
            if (m == 1) a_dst2[orow] = acca[r];   // col 1 = dst projection
        }
    }
}

// ---------------- Layer 2 aggregation + sigmoid (f32 out) -------------------
__global__ __launch_bounds__(256) void agg2_k(
    const int* __restrict__ offs, const int* __restrict__ csr_src,
    const float* __restrict__ a_src2, const float* __restrict__ a_dst2,
    const bf16* __restrict__ h2, const float* __restrict__ b2,
    float* __restrict__ out) {
    int wv = threadIdx.x >> 6;
    int lane = threadIdx.x & 63;
    int dst = blockIdx.x * 4 + wv;
    if (dst >= NN) return;
    int start = offs[dst], end = offs[dst + 1];
    float adst = a_dst2[dst];
    float acc = 0.f, dsum = 0.f;
    for (int t0 = start; t0 < end; t0 += 64) {
        int n = end - t0; if (n > 64) n = 64;
        float wr = 0.f; int sr = 0;
        if (lane < n) {
            sr = csr_src[t0 + lane];
            wr = __expf(lrelu(a_src2[sr] + adst));
        }
        dsum += wr;
        int j = 0;
        for (; j + 4 <= n; j += 4) {
            float w0 = __shfl(wr, j, 64),     w1 = __shfl(wr, j + 1, 64);
            float w2 = __shfl(wr, j + 2, 64), w3 = __shfl(wr, j + 3, 64);
            int s0 = __shfl(sr, j, 64),       s1 = __shfl(sr, j + 1, 64);
            int s2 = __shfl(sr, j + 2, 64),   s3 = __shfl(sr, j + 3, 64);
            float h0 = b2f(h2[(size_t)s0 * 64 + lane]);
            float h1v = b2f(h2[(size_t)s1 * 64 + lane]);
            float h2v = b2f(h2[(size_t)s2 * 64 + lane]);
            float h3 = b2f(h2[(size_t)s3 * 64 + lane]);
            acc += w0 * h0 + w1 * h1v + w2 * h2v + w3 * h3;
        }
        for (; j < n; ++j) {
            float wj = __shfl(wr, j, 64);
            int sj = __shfl(sr, j, 64);
            acc += wj * b2f(h2[(size_t)sj * 64 + lane]);
        }
    }
#pragma unroll
    for (int o = 32; o >= 1; o >>= 1) dsum += __shfl_xor(dsum, o, 64);
    float o = acc / (dsum + 1e-16f) + b2[lane];
    out[(size_t)dst * 64 + lane] = 1.f / (1.f + __expf(-o));
}

// ---------------- host ------------------------------------------------------

extern "C" void kernel_launch(void* const* d_in, const int* in_sizes, int n_in,
                              void* d_out, int out_size, void* d_ws, size_t ws_size,
                              hipStream_t stream) {
    const float* x    = (const float*)d_in[0];
    const void*  ei   = d_in[1];
    const float* W1   = (const float*)d_in[2];
    const float* asr1 = (const float*)d_in[3];
    const float* ads1 = (const float*)d_in[4];
    const float* b1   = (const float*)d_in[5];
    const float* W2   = (const float*)d_in[6];
    const float* asr2 = (const float*)d_in[7];
    const float* ads2 = (const float*)d_in[8];
    const float* b2   = (const float*)d_in[9];
    float* out = (float*)d_out;

    char* w = (char*)d_ws;
    auto carve = [&](size_t bytes) {
        void* p = (void*)w;
        w += (bytes + 255) & ~(size_t)255;
        return p;
    };
    int*    csr_raw  = (int*)carve((size_t)TE * 4);            // 3.4 MB
    int*    csr_can  = (int*)carve((size_t)TE * 4);            // 3.4 MB
    int*    offs     = (int*)carve((size_t)(NN + 1) * 4);
    int*    deg      = (int*)carve((size_t)NN * 4);
    int*    chunkoff = (int*)carve(256 * 4);
    float*  a_src1   = (float*)carve((size_t)NN * 16 * 4);     // 3.2 MB
    float*  a_dst1   = (float*)carve((size_t)NN * 16 * 4);     // 3.2 MB
    unsigned short* W1T  = (unsigned short*)carve(128 * 256 * 2);  // 64 KB
    unsigned short* W2T  = (unsigned short*)carve(256 * 64 * 2);   // 32 KB
    unsigned short* P1sT = (unsigned short*)carve(16 * 128 * 2);   // 4 KB
    unsigned short* P1dT = (unsigned short*)carve(16 * 128 * 2);   // 4 KB
    unsigned short* P2T  = (unsigned short*)carve(16 * 256 * 2);   // 8 KB
    bf16*   h1       = (bf16*)carve((size_t)NN * 256 * 2);     // 25.6 MB
    bf16*   out1     = (bf16*)carve((size_t)NN * 256 * 2);     // 25.6 MB
    // layer-2 buffers alias h1 (dead after agg1)
    char*   l2base   = (char*)h1;
    bf16*   h2       = (bf16*)l2base;
    float*  a_src2   = (float*)(l2base + (size_t)NN * 64 * 2);
    float*  a_dst2   = a_src2 + NN;

    hipMemsetAsync(deg, 0, (size_t)NN * 4, stream);

    const int pgrid = ((TE + 1) / 2 + 255) / 256;
    count_deg_k<<<pgrid, 256, 0, stream>>>(ei, deg, W1, W2, asr1, ads1, asr2, ads2,
                                           W1T, W2T, P1sT, P1dT, P2T);
    scan_chunks_k<<<1, 256, 0, stream>>>(deg, chunkoff);
    scan_within_k<<<NCH, 256, 0, stream>>>(deg, chunkoff, offs);
    fill_csr_k<<<pgrid, 256, 0, stream>>>(ei, offs, deg, csr_raw);

    gemm1_k<<<(NN + 63) / 64, 256, 0, stream>>>(x, W1T, P1sT, P1dT, h1, a_src1, a_dst1);
    agg1_k<<<NN / 4, 256, 0, stream>>>(offs, csr_raw, csr_can, a_src1, a_dst1, h1, b1, out1);
    gemm2_k<<<(NN + 63) / 64, 256, 0, stream>>>(out1, W2T, P2T, h2, a_src2, a_dst2);
    agg2_k<<<(NN + 3) / 4, 256, 0, stream>>>(offs, csr_can, a_src2, a_dst2, h2, b2, out);
}